// Round 8
// baseline (433.833 us; speedup 1.0000x reference)
//
#include <hip/hip_runtime.h>
#include <math.h>

#define IMG_H 1024
#define IMG_W 1024
#define OUT_H 1025
#define OUT_W 1025
#define NIMG  16
#define TOTAL ((size_t)NIMG * OUT_H * OUT_W)

#define TILE_W 64
#define TILE_H 16
#define NTILES 4                  // vertical tiles per block -> 64 rows/block
#define HALO_W 68                 // ox in [tile_ox-2, tile_ox+65]
#define HALO_H 18                 // oy in [tile_oy-1, tile_oy+16]
#define NQX    17                 // 68/4 x-quads per halo row
#define NQUAD  (HALO_H * NQX)     // 306
#define NTHREADS 320

// Map bp (double-reflect-padded) row/col index k in [0,1026] to source image index.
__device__ __forceinline__ int refl(int k) {
    if (k >= 2) return (k <= 1025) ? (k - 2) : 1022;
    return k;
}

// Generic sobel at output (i,j) — exact f32 op order (bit-matched np in r1-r7).
__device__ __forceinline__ void sobel_generic(const float* __restrict__ img, int i, int j,
                                              float& gx, float& gy) {
    int r0 = refl(i), r1 = refl(i + 1), r2 = refl(i + 2);
    int c0 = refl(j), c1 = refl(j + 1), c2 = refl(j + 2);
    const float* p0 = img + r0 * IMG_W;
    const float* p1 = img + r1 * IMG_W;
    const float* p2 = img + r2 * IMG_W;
    float v00 = p0[c0], v01 = p0[c1], v02 = p0[c2];
    float v10 = p1[c0],               v12 = p1[c2];
    float v20 = p2[c0], v21 = p2[c1], v22 = p2[c2];

    float t = -v00;
    t = __fadd_rn(t, v02);
    t = __fadd_rn(t, -2.0f * v10);
    t = __fadd_rn(t, 2.0f * v12);
    t = __fadd_rn(t, -v20);
    gx = __fadd_rn(t, v22);

    t = -v00;
    t = __fadd_rn(t, -2.0f * v01);
    t = __fadd_rn(t, -v02);
    t = __fadd_rn(t, v20);
    t = __fadd_rn(t, 2.0f * v21);
    gy = __fadd_rn(t, v22);
}

// Exact reference binning (double atan2 -> f32 chain). Bit-matched np in r1.
__device__ int classify_slow(float gx, float gy) {
    float t = (float)atan2((double)gx, (double)gy);
    float deg = __fmul_rn(t, (float)(180.0 / M_PI));
    float th = __fadd_rn(deg, 90.0f);
    th = fmodf(th, 180.0f);
    if (th < 0.0f) th += 180.0f;
    if (th < 22.5f || th >= 157.5f) return 0;
    if (th < 67.5f) return 1;
    if (th < 112.5f) return 2;
    return 3;
}

// Branchless fast binning with guard band; rare lanes defer to the exact chain.
// Decision semantics identical to r2-r7 (bit-matched np).
__device__ __forceinline__ int classify(float gx, float gy) {
    float ax = fabsf(gx), ay = fabsf(gy);
    const float T22_LO = 0.414172141e0f;
    const float T22_HI = 0.414254984e0f;
    const float T67_LO = 2.413972141e0f;
    const float T67_HI = 2.414454984e0f;

    bool in22 = (ax > ay * T22_LO) && (ax < ay * T22_HI);
    bool in67 = (ax > ay * T67_LO) && (ax < ay * T67_HI);
    if (__builtin_expect(in22 || in67, 0))
        return classify_slow(gx, gy);

    unsigned s = (__float_as_uint(gx) ^ __float_as_uint(gy)) >> 31;
    int diag = s ? 1 : 3;
    return (ax <= ay * T22_LO) ? 2 : ((ax >= ay * T67_HI) ? 0 : diag);
}

__device__ __forceinline__ float mag(float gx, float gy) {
    return __fsqrt_rn(__fadd_rn(__fmul_rn(gx, gx), __fmul_rn(gy, gy)));
}

__device__ __forceinline__ void load6(const float* __restrict__ p, float v[6]) {
    float4 a = *(const float4*)p;        // 16B aligned: col base ≡ 0 (mod 4)
    float2 b = *(const float2*)(p + 4);
    v[0] = a.x; v[1] = a.y; v[2] = a.z; v[3] = a.w; v[4] = b.x; v[5] = b.y;
}

__global__ __launch_bounds__(NTHREADS) void canny_kernel(const float* __restrict__ images,
                                                         float* __restrict__ out) {
    __shared__ float    g_s[2][HALO_H * HALO_W];
    __shared__ unsigned b_u[2][HALO_H * NQX];

    const int tile_ox = blockIdx.x * TILE_W;
    const int base_oy = blockIdx.y * (TILE_H * NTILES);
    const int n       = blockIdx.z;
    const float* img = images + (size_t)n * IMG_H * IMG_W;
    const int t = threadIdx.x;

    // Fixed quad coordinates (valid when t < NQUAD).
    const int hy  = t / NQX;
    const int qx  = t - hy * NQX;
    const int ox0 = tile_ox + qx * 4 - 2;   // ≡ 2 (mod 4)

    float* const out_i = out;
    float* const out_w = out + TOTAL;
    float* const out_s = out + 2 * TOTAL;

    // Prefetched phase-1 rows for the upcoming tile (interior fast path only).
    float F0[6], F1[6], F2[6];
    bool  pf_int = false;

    // ---- prologue: issue tile-0 loads ----
    if (t < NQUAD) {
        int oy = base_oy + hy - 1;
        pf_int = (oy >= 2 && oy <= 1023 && ox0 >= 2 && ox0 <= 1020);
        if (pf_int) {
            const float* rp = img + (oy - 2) * IMG_W + (ox0 - 2);
            load6(rp, F0);
            load6(rp + IMG_W, F1);
            load6(rp + 2 * IMG_W, F2);
        }
    }

    int cur = 0;
    for (int tt = 0; tt < NTILES; ++tt) {
        const int tile_oy = base_oy + tt * TILE_H;
        const bool live = (tile_oy < OUT_H);

        // ---- Phase 1: g + bin into LDS[cur] (from prefetched regs) ----
        if (live && t < NQUAD) {
            int oy = tile_oy + hy - 1;
            float    gq[4];
            unsigned bq[4];
            if (pf_int) {
                #pragma unroll
                for (int p = 0; p < 4; p++) {
                    float v00 = F0[p], v01 = F0[p + 1], v02 = F0[p + 2];
                    float v10 = F1[p],                  v12 = F1[p + 2];
                    float v20 = F2[p], v21 = F2[p + 1], v22 = F2[p + 2];

                    float s = -v00;
                    s = __fadd_rn(s, v02);
                    s = __fadd_rn(s, -2.0f * v10);
                    s = __fadd_rn(s, 2.0f * v12);
                    s = __fadd_rn(s, -v20);
                    float gx = __fadd_rn(s, v22);

                    s = -v00;
                    s = __fadd_rn(s, -2.0f * v01);
                    s = __fadd_rn(s, -v02);
                    s = __fadd_rn(s, v20);
                    s = __fadd_rn(s, 2.0f * v21);
                    float gy = __fadd_rn(s, v22);

                    gq[p] = mag(gx, gy);
                    bq[p] = (unsigned)classify(gx, gy);
                }
            } else {
                #pragma unroll
                for (int p = 0; p < 4; p++) {
                    int ox = ox0 + p;
                    float g = -1.0f;
                    unsigned b = 255u;
                    if (oy >= 0 && oy < OUT_H && ox >= 0 && ox < OUT_W) {
                        float gx, gy;
                        sobel_generic(img, oy, ox, gx, gy);
                        g = mag(gx, gy);
                        b = (unsigned)classify(gx, gy);
                    }
                    gq[p] = g;
                    bq[p] = b;
                }
            }
            int ldoff = hy * HALO_W + qx * 4;
            *(float4*)&g_s[cur][ldoff] = make_float4(gq[0], gq[1], gq[2], gq[3]);
            b_u[cur][hy * NQX + qx] = bq[0] | (bq[1] << 8) | (bq[2] << 16) | (bq[3] << 24);
        }
        __syncthreads();

        // ---- issue next tile's loads (in flight during phase 2) ----
        if (tt + 1 < NTILES && (tile_oy + TILE_H) < OUT_H && t < NQUAD) {
            int oy = tile_oy + TILE_H + hy - 1;
            pf_int = (oy >= 2 && oy <= 1023 && ox0 >= 2 && ox0 <= 1020);
            if (pf_int) {
                const float* rp = img + (oy - 2) * IMG_W + (ox0 - 2);
                load6(rp, F0);
                load6(rp + IMG_W, F1);
                load6(rp + 2 * IMG_W, F2);
            }
        }

        // ---- Phase 2: NMS + thresholds from LDS[cur] (dense mapping) ----
        if (live) {
            const float* gs = g_s[cur];
            const unsigned char* b_s = (const unsigned char*)b_u[cur];
            #pragma unroll
            for (int q = 0; q < 4; q++) {
                int p = t + NTHREADS * q;
                if (p >= TILE_W * TILE_H) break;         // only q=3 is partial
                int r = p >> 6, c = p & 63;
                int oy = tile_oy + r, ox = tile_ox + c;
                if (oy >= OUT_H || ox >= OUT_W) continue;

                int hc = (r + 1) * HALO_W + (c + 2);
                float gc = gs[hc];
                int   bc = b_s[hc];

                int doff = (bc == 0) ? 1
                         : (bc == 1) ? (HALO_W - 1)
                         : (bc == 2) ? HALO_W
                         :             (HALO_W + 1);

                float nmax = 0.0f;
                float g1 = gs[hc + doff];
                if (b_s[hc + doff] == bc && g1 > nmax) nmax = g1;
                float g2 = gs[hc - doff];
                if (b_s[hc - doff] == bc && g2 > nmax) nmax = g2;

                float e = (gc >= nmax) ? gc : 0.0f;

                size_t o = (size_t)(n * OUT_H + oy) * OUT_W + ox;
                out_i[o] = (e >= 50.0f) ? 255.5f : 0.0f;
                out_w[o] = (e >= 50.0f && e < 100.0f) ? 255.0f : 0.0f;
                out_s[o] = (e >= 100.0f) ? 255.0f : 0.0f;
            }
        }
        cur ^= 1;
    }
}

extern "C" void kernel_launch(void* const* d_in, const int* in_sizes, int n_in,
                              void* d_out, int out_size, void* d_ws, size_t ws_size,
                              hipStream_t stream) {
    const float* images = (const float*)d_in[0];
    float* out = (float*)d_out;
    dim3 grid((OUT_W + TILE_W - 1) / TILE_W,                 // 17
              (OUT_H + TILE_H * NTILES - 1) / (TILE_H * NTILES),  // 17
              NIMG);                                          // 16
    canny_kernel<<<grid, NTHREADS, 0, stream>>>(images, out);
}

// Round 9
// 351.006 us; speedup vs baseline: 1.2360x; 1.2360x over previous
//
#include <hip/hip_runtime.h>
#include <math.h>

#define IMG_H 1024
#define IMG_W 1024
#define OUT_H 1025
#define OUT_W 1025
#define NIMG  16
#define TOTAL ((size_t)NIMG * OUT_H * OUT_W)

#define TILE_W 64
#define TILE_H 10
#define HALO_W 68                 // ox in [tile_ox-2, tile_ox+65]
#define HALO_H 12                 // oy in [tile_oy-1, tile_oy+10]
#define NQX    17                 // 68/4 x-quads per halo row
#define NQUAD  (HALO_H * NQX)     // 204
#define NTHREADS 128              // 2 waves -> up to 16 blocks/CU resident

// Map bp (double-reflect-padded) row/col index k in [0,1026] to source image index.
__device__ __forceinline__ int refl(int k) {
    if (k >= 2) return (k <= 1025) ? (k - 2) : 1022;
    return k;
}

// Generic sobel at output (i,j) — exact f32 op order (bit-matched np in r1-r8).
__device__ __forceinline__ void sobel_generic(const float* __restrict__ img, int i, int j,
                                              float& gx, float& gy) {
    int r0 = refl(i), r1 = refl(i + 1), r2 = refl(i + 2);
    int c0 = refl(j), c1 = refl(j + 1), c2 = refl(j + 2);
    const float* p0 = img + r0 * IMG_W;
    const float* p1 = img + r1 * IMG_W;
    const float* p2 = img + r2 * IMG_W;
    float v00 = p0[c0], v01 = p0[c1], v02 = p0[c2];
    float v10 = p1[c0],               v12 = p1[c2];
    float v20 = p2[c0], v21 = p2[c1], v22 = p2[c2];

    float t = -v00;
    t = __fadd_rn(t, v02);
    t = __fadd_rn(t, -2.0f * v10);
    t = __fadd_rn(t, 2.0f * v12);
    t = __fadd_rn(t, -v20);
    gx = __fadd_rn(t, v22);

    t = -v00;
    t = __fadd_rn(t, -2.0f * v01);
    t = __fadd_rn(t, -v02);
    t = __fadd_rn(t, v20);
    t = __fadd_rn(t, 2.0f * v21);
    gy = __fadd_rn(t, v22);
}

// Exact reference binning (double atan2 -> f32 chain). Bit-matched np in r1.
__device__ int classify_slow(float gx, float gy) {
    float t = (float)atan2((double)gx, (double)gy);
    float deg = __fmul_rn(t, (float)(180.0 / M_PI));
    float th = __fadd_rn(deg, 90.0f);
    th = fmodf(th, 180.0f);
    if (th < 0.0f) th += 180.0f;
    if (th < 22.5f || th >= 157.5f) return 0;
    if (th < 67.5f) return 1;
    if (th < 112.5f) return 2;
    return 3;
}

// Branchless fast binning with guard band; rare lanes defer to the exact chain.
// Decision semantics identical to r2-r8 (bit-matched np).
__device__ __forceinline__ int classify(float gx, float gy) {
    float ax = fabsf(gx), ay = fabsf(gy);
    const float T22_LO = 0.414172141e0f;
    const float T22_HI = 0.414254984e0f;
    const float T67_LO = 2.413972141e0f;
    const float T67_HI = 2.414454984e0f;

    bool in22 = (ax > ay * T22_LO) && (ax < ay * T22_HI);
    bool in67 = (ax > ay * T67_LO) && (ax < ay * T67_HI);
    if (__builtin_expect(in22 || in67, 0))
        return classify_slow(gx, gy);

    unsigned s = (__float_as_uint(gx) ^ __float_as_uint(gy)) >> 31;
    int diag = s ? 1 : 3;
    return (ax <= ay * T22_LO) ? 2 : ((ax >= ay * T67_HI) ? 0 : diag);
}

__device__ __forceinline__ float mag(float gx, float gy) {
    return __fsqrt_rn(__fadd_rn(__fmul_rn(gx, gx), __fmul_rn(gy, gy)));
}

__device__ __forceinline__ void load6(const float* __restrict__ p, float v[6]) {
    float4 a = *(const float4*)p;        // 16B aligned: col base ≡ 0 (mod 4)
    float2 b = *(const float2*)(p + 4);
    v[0] = a.x; v[1] = a.y; v[2] = a.z; v[3] = a.w; v[4] = b.x; v[5] = b.y;
}

__global__ __launch_bounds__(NTHREADS, 8) void canny_kernel(const float* __restrict__ images,
                                                            float* __restrict__ out) {
    // (g, bin) interleaved: .x = magnitude, .y = bin as bit pattern.
    __shared__ float2 gb_s[HALO_H * HALO_W];   // 6528 B

    const int tile_ox = blockIdx.x * TILE_W;
    const int tile_oy = blockIdx.y * TILE_H;
    const int n       = blockIdx.z;
    const float* img = images + (size_t)n * IMG_H * IMG_W;
    const int t = threadIdx.x;

    // ---- Phase 1: g + bin for the 12x68 halo, one x-quad per thread-pass ----
    for (int idx = t; idx < NQUAD; idx += NTHREADS) {
        int hy  = idx / NQX;
        int qx  = idx - hy * NQX;
        int oy  = tile_oy + hy - 1;
        int ox0 = tile_ox + qx * 4 - 2;   // ≡ 2 (mod 4)

        float    gq[4];
        unsigned bq[4];

        if (oy >= 2 && oy <= 1023 && ox0 >= 2 && ox0 <= 1020) {
            // Interior fast path: rows oy-2..oy, cols ox0-2..ox0+3, no reflection.
            const float* r0p = img + (oy - 2) * IMG_W + (ox0 - 2);
            float R0[6], R1[6], R2[6];
            load6(r0p, R0);
            load6(r0p + IMG_W, R1);
            load6(r0p + 2 * IMG_W, R2);
            #pragma unroll
            for (int p = 0; p < 4; p++) {
                float v00 = R0[p], v01 = R0[p + 1], v02 = R0[p + 2];
                float v10 = R1[p],                  v12 = R1[p + 2];
                float v20 = R2[p], v21 = R2[p + 1], v22 = R2[p + 2];

                float s = -v00;
                s = __fadd_rn(s, v02);
                s = __fadd_rn(s, -2.0f * v10);
                s = __fadd_rn(s, 2.0f * v12);
                s = __fadd_rn(s, -v20);
                float gx = __fadd_rn(s, v22);

                s = -v00;
                s = __fadd_rn(s, -2.0f * v01);
                s = __fadd_rn(s, -v02);
                s = __fadd_rn(s, v20);
                s = __fadd_rn(s, 2.0f * v21);
                float gy = __fadd_rn(s, v22);

                gq[p] = mag(gx, gy);
                bq[p] = (unsigned)classify(gx, gy);
            }
        } else {
            // Boundary quad: per-pixel generic (reflection + bounds).
            #pragma unroll
            for (int p = 0; p < 4; p++) {
                int ox = ox0 + p;
                float g = -1.0f;
                unsigned b = 255u;
                if (oy >= 0 && oy < OUT_H && ox >= 0 && ox < OUT_W) {
                    float gx, gy;
                    sobel_generic(img, oy, ox, gx, gy);
                    g = mag(gx, gy);
                    b = (unsigned)classify(gx, gy);
                }
                gq[p] = g;
                bq[p] = b;
            }
        }

        float2* dst = &gb_s[hy * HALO_W + qx * 4];   // 32B contiguous, 16B aligned
        dst[0] = make_float2(gq[0], __uint_as_float(bq[0]));
        dst[1] = make_float2(gq[1], __uint_as_float(bq[1]));
        dst[2] = make_float2(gq[2], __uint_as_float(bq[2]));
        dst[3] = make_float2(gq[3], __uint_as_float(bq[3]));
    }
    __syncthreads();

    // ---- Phase 2: NMS + thresholds from LDS (dense mapping, b64 reads) ----
    float* const out_i = out;
    float* const out_w = out + TOTAL;
    float* const out_s = out + 2 * TOTAL;
    #pragma unroll
    for (int q = 0; q < (TILE_W * TILE_H) / NTHREADS; q++) {   // 5 full passes
        int p = t + NTHREADS * q;
        int r = p >> 6, c = p & 63;
        int oy = tile_oy + r, ox = tile_ox + c;
        if (oy >= OUT_H || ox >= OUT_W) continue;

        int hc = (r + 1) * HALO_W + (c + 2);
        float2 cb = gb_s[hc];
        float    gc = cb.x;
        unsigned bc = __float_as_uint(cb.y);

        int doff = (bc == 0) ? 1
                 : (bc == 1) ? (HALO_W - 1)
                 : (bc == 2) ? HALO_W
                 :             (HALO_W + 1);

        float2 nb1 = gb_s[hc + doff];
        float2 nb2 = gb_s[hc - doff];
        float m1 = (__float_as_uint(nb1.y) == bc) ? nb1.x : 0.0f;  // OOB bin=255 never matches
        float m2 = (__float_as_uint(nb2.y) == bc) ? nb2.x : 0.0f;
        float nmax = fmaxf(m1, m2);
        float e = (gc >= nmax) ? gc : 0.0f;

        size_t o = (size_t)(n * OUT_H + oy) * OUT_W + ox;
        out_i[o] = (e >= 50.0f) ? 255.5f : 0.0f;
        out_w[o] = (e >= 50.0f && e < 100.0f) ? 255.0f : 0.0f;
        out_s[o] = (e >= 100.0f) ? 255.0f : 0.0f;
    }
}

extern "C" void kernel_launch(void* const* d_in, const int* in_sizes, int n_in,
                              void* d_out, int out_size, void* d_ws, size_t ws_size,
                              hipStream_t stream) {
    const float* images = (const float*)d_in[0];
    float* out = (float*)d_out;
    dim3 grid((OUT_W + TILE_W - 1) / TILE_W,    // 17
              (OUT_H + TILE_H - 1) / TILE_H,    // 103
              NIMG);                             // 16
    canny_kernel<<<grid, NTHREADS, 0, stream>>>(images, out);
}